// Round 8
// baseline (131.249 us; speedup 1.0000x reference)
//
#include <hip/hip_runtime.h>
#include <hip/hip_bf16.h>

typedef __bf16 bf16_t;
typedef __bf16 bf16x8 __attribute__((ext_vector_type(8)));
typedef __bf16 bf16x4 __attribute__((ext_vector_type(4)));
typedef float f32x4 __attribute__((ext_vector_type(4)));

#define AS1 __attribute__((address_space(1)))
#define AS3 __attribute__((address_space(3)))

// ---------------------------------------------------------------------------
// fused fp32 -> bf16 conversion for all three inputs (one dispatch).
// ---------------------------------------------------------------------------
__global__ __launch_bounds__(256)
void cvt_all(const float* __restrict__ in, bf16_t* __restrict__ o_in,
             const float* __restrict__ fw, bf16_t* __restrict__ o_fw,
             const float* __restrict__ bw, bf16_t* __restrict__ o_bw) {
    int i = blockIdx.x * 256 + threadIdx.x;
    const float* s;
    bf16_t* d;
    int k;
    if (i < 786432)      { s = in; d = o_in; k = i; }
    else if (i < 811008) { s = fw; d = o_fw; k = i - 786432; }
    else if (i < 909312) { s = bw; d = o_bw; k = i - 811008; }
    else return;
    float4 a = ((const float4*)s)[k * 2];
    float4 b = ((const float4*)s)[k * 2 + 1];
    bf16x8 v;
    v[0] = (bf16_t)a.x; v[1] = (bf16_t)a.y; v[2] = (bf16_t)a.z; v[3] = (bf16_t)a.w;
    v[4] = (bf16_t)b.x; v[5] = (bf16_t)b.y; v[6] = (bf16_t)b.z; v[7] = (bf16_t)b.w;
    ((bf16x8*)d)[k] = v;
}

// ---------------------------------------------------------------------------
// gemm_bt (m97 structure) — GEMM1 only (128x64 tile, 256 blocks, 1 round).
// ---------------------------------------------------------------------------
template <int BM, int BN, int EPI>
__global__ __launch_bounds__(256)
void gemm_bt(const bf16_t* __restrict__ A, const bf16_t* __restrict__ Bm,
             void* __restrict__ Cv, const float* __restrict__ bias,
             int M, int N, int K) {
    constexpr int MR = BM / 32;
    constexpr int NR = BN / 32;
    typedef float fvec __attribute__((ext_vector_type(NR)));
    typedef bf16_t bvec __attribute__((ext_vector_type(NR)));

    __shared__ bf16_t As[BM * 64];
    __shared__ bf16_t Bs[BN * 64];

    const int tid  = threadIdx.x;
    const int lane = tid & 63;
    const int wave = tid >> 6;
    const int mblk = blockIdx.x, nblk = blockIdx.y;

    const bf16_t* Ab = A + (long)mblk * BM * K;
    const bf16_t* Bb = Bm + (long)nblk * BN * K;

    f32x4 acc[MR][NR] = {};

    const int wrow = (wave >> 1) * (BM / 2);
    const int wcol = (wave & 1) * (BN / 2);
    const int lrow = lane & 15;
    const int kgrp = lane >> 4;

    for (int k0 = 0; k0 < K; k0 += 64) {
#pragma unroll
        for (int it = 0; it < MR; ++it) {
            const int chunk = it * 256 + tid;
            const int row = chunk >> 3, c8 = chunk & 7;
            __builtin_amdgcn_global_load_lds(
                (const AS1 void*)(Ab + (long)row * K + k0 + c8 * 8),
                (AS3 void*)(As + chunk * 8), 16, 0, 0);
        }
#pragma unroll
        for (int it = 0; it < NR; ++it) {
            const int chunk = it * 256 + tid;
            const int row = chunk >> 3, c8 = chunk & 7;
            __builtin_amdgcn_global_load_lds(
                (const AS1 void*)(Bb + (long)row * K + k0 + c8 * 8),
                (AS3 void*)(Bs + chunk * 8), 16, 0, 0);
        }
        __syncthreads();

#pragma unroll
        for (int kk = 0; kk < 64; kk += 32) {
            const int koff = kk + kgrp * 8;
            bf16x8 af[MR], bfr[NR];
#pragma unroll
            for (int m = 0; m < MR; ++m)
                af[m] = *(const bf16x8*)(As + (wrow + m * 16 + lrow) * 64 + koff);
#pragma unroll
            for (int n = 0; n < NR; ++n)
                bfr[n] = *(const bf16x8*)(Bs + (wcol + lrow * NR + n) * 64 + koff);
#pragma unroll
            for (int m = 0; m < MR; ++m)
#pragma unroll
                for (int n = 0; n < NR; ++n)
                    acc[m][n] = __builtin_amdgcn_mfma_f32_16x16x32_bf16(af[m], bfr[n], acc[m][n], 0, 0, 0);
        }
        __syncthreads();
    }

    const long rbase = (long)mblk * BM + wrow + kgrp * 4;
    const long cb0   = (long)nblk * BN + wcol + lrow * NR;
    bf16_t* C = (bf16_t*)Cv;
    const float* bp = bias + cb0;
    fvec bv = *(const fvec*)bp;
#pragma unroll
    for (int m = 0; m < MR; ++m)
#pragma unroll
        for (int j = 0; j < 4; ++j) {
            bvec v;
#pragma unroll
            for (int n = 0; n < NR; ++n) v[n] = (bf16_t)(acc[m][n][j] + bv[n]);
            *(bvec*)(C + (rbase + m * 16 + j) * N + cb0) = v;
        }
}

// ---------------------------------------------------------------------------
// 8-phase 256x256 GEMM, K=256 — GEMM2 only (compute-bound, bf16 out).
// ---------------------------------------------------------------------------
template <int EPI, int XCD, int NMB, int NNB>
__global__ __launch_bounds__(512, 2)
void gemm8p(const bf16_t* __restrict__ A, const bf16_t* __restrict__ Bm,
            void* __restrict__ Cv, const float* __restrict__ bias,
            int N, long sA, long sB, long sC) {
    constexpr int K = 256;
    extern __shared__ bf16_t lds[];

    const int tid  = threadIdx.x;
    const int lane = tid & 63;
    const int wave = tid >> 6;
    const int wm = wave >> 2, wn = wave & 3;
    const int lrow = lane & 15, kgrp = lane >> 4;

    int mblk, nblk, bz;
    {
        int L = blockIdx.x;
        if (XCD) { bz = L & 7; int w = L >> 3; nblk = w % NNB; mblk = w / NNB; }
        else     { bz = 0;     mblk = L % NMB; nblk = L / NMB; }
    }

    const bf16_t* Ab = A + (long)bz * sA + (long)mblk * 256 * K;
    const bf16_t* Bb = Bm + (long)bz * sB + (long)nblk * 256 * K;

    const int c0 = tid, c1 = 512 + tid;
    const int r0 = c0 >> 3, r1 = c1 >> 3;
    const int ca0 = (c0 & 7) ^ (r0 & 7),        ca1 = (c1 & 7) ^ (r1 & 7);
    const int cb0 = (c0 & 7) ^ ((r0 >> 2) & 7), cb1 = (c1 & 7) ^ ((r1 >> 2) & 7);

    auto stageA = [&](int t, int h) {
        const bf16_t* s0 = Ab + (long)(h * 128 + r0) * K + t * 64 + ca0 * 8;
        const bf16_t* s1 = Ab + (long)(h * 128 + r1) * K + t * 64 + ca1 * 8;
        bf16_t* d = lds + ((t & 1) * 2 + h) * 8192;
        __builtin_amdgcn_global_load_lds((const AS1 void*)s0, (AS3 void*)(d + c0 * 8), 16, 0, 0);
        __builtin_amdgcn_global_load_lds((const AS1 void*)s1, (AS3 void*)(d + c1 * 8), 16, 0, 0);
    };
    auto stageB = [&](int t, int h) {
        const bf16_t* s0 = Bb + (long)(h * 128 + r0) * K + t * 64 + cb0 * 8;
        const bf16_t* s1 = Bb + (long)(h * 128 + r1) * K + t * 64 + cb1 * 8;
        bf16_t* d = lds + 32768 + ((t & 1) * 2 + h) * 8192;
        __builtin_amdgcn_global_load_lds((const AS1 void*)s0, (AS3 void*)(d + c0 * 8), 16, 0, 0);
        __builtin_amdgcn_global_load_lds((const AS1 void*)s1, (AS3 void*)(d + c1 * 8), 16, 0, 0);
    };
    auto ldA = [&](int t, int mf, int kk) -> bf16x8 {
        const int row = mf * 16 + lrow;
        const int col = (kk * 32 + kgrp * 8) ^ ((row & 7) << 3);
        return *(const bf16x8*)(lds + ((t & 1) * 2 + wm) * 8192 + row * 64 + col);
    };
    auto ldB = [&](int t, int g, int kk) -> bf16x8 {
        const int row = (wn & 1) * 64 + lrow * 4 + g;
        const int col = (kk * 32 + kgrp * 8) ^ (((row >> 2) & 7) << 3);
        return *(const bf16x8*)(lds + 32768 + ((t & 1) * 2 + (wn >> 1)) * 8192 + row * 64 + col);
    };

    f32x4 acc[8][4] = {};
    bf16x8 bfr[4][2];

    stageA(0, 0); stageA(0, 1); stageB(0, 0); stageB(0, 1); stageB(1, 0); stageB(1, 1);
    asm volatile("s_waitcnt vmcnt(4)" ::: "memory");
    __builtin_amdgcn_s_barrier();

#pragma unroll
    for (int i = 0; i < 2; ++i) {
#pragma unroll
        for (int p = 0; p < 8; ++p) {
            const int q = p & 3;
            const int t = 2 * i + (p >> 2);
            bf16x8 af[2][2];
            if (q == 0) {
#pragma unroll
                for (int g = 0; g < 4; ++g) { bfr[g][0] = ldB(t, g, 0); bfr[g][1] = ldB(t, g, 1); }
            }
#pragma unroll
            for (int mm = 0; mm < 2; ++mm) { af[mm][0] = ldA(t, 2 * q + mm, 0); af[mm][1] = ldA(t, 2 * q + mm, 1); }

            if (p == 0) stageA(2 * i + 1, 0);
            else if (p == 1) stageA(2 * i + 1, 1);
            else if (p == 2) { if (2 * i + 2 < 4) stageB(2 * i + 2, 0); }
            else if (p == 3) { if (2 * i + 2 < 4) stageB(2 * i + 2, 1); }
            else if (p == 4) { if (2 * i + 2 < 4) stageA(2 * i + 2, 0); }
            else if (p == 5) { if (2 * i + 2 < 4) stageA(2 * i + 2, 1); }
            else if (p == 6) { if (2 * i + 3 < 4) stageB(2 * i + 3, 0); }
            else             { if (2 * i + 3 < 4) stageB(2 * i + 3, 1); }

            __builtin_amdgcn_s_barrier();
            asm volatile("s_waitcnt lgkmcnt(0)" ::: "memory");
            __builtin_amdgcn_s_setprio(1);
#pragma unroll
            for (int mm = 0; mm < 2; ++mm)
#pragma unroll
                for (int g = 0; g < 4; ++g)
#pragma unroll
                    for (int kk = 0; kk < 2; ++kk)
                        acc[2 * q + mm][g] = __builtin_amdgcn_mfma_f32_16x16x32_bf16(
                            af[mm][kk], bfr[g][kk], acc[2 * q + mm][g], 0, 0, 0);
            __builtin_amdgcn_s_setprio(0);

            if (p == 3) {
                if (2 * i + 2 < 4) asm volatile("s_waitcnt vmcnt(4)" ::: "memory");
                else               asm volatile("s_waitcnt vmcnt(0)" ::: "memory");
            } else if (p == 7) {
                if (2 * i + 2 < 4) asm volatile("s_waitcnt vmcnt(4)" ::: "memory");
            }
            __builtin_amdgcn_s_barrier();
        }
    }

    const long rb = (long)mblk * 256 + wm * 128 + kgrp * 4;
    const long cb = (long)nblk * 256 + wn * 64 + lrow * 4;
    if constexpr (EPI == 0) {
        float* C = (float*)Cv + (long)bz * sC;
#pragma unroll
        for (int m = 0; m < 8; ++m)
#pragma unroll
            for (int j = 0; j < 4; ++j) {
                f32x4 v = { acc[m][0][j], acc[m][1][j], acc[m][2][j], acc[m][3][j] };
                __builtin_nontemporal_store(v, (f32x4*)(C + (rb + m * 16 + j) * N + cb));
            }
    } else {
        bf16_t* C = (bf16_t*)Cv;
        f32x4 bv = *(const f32x4*)(bias + (int)(cb & 255));
#pragma unroll
        for (int m = 0; m < 8; ++m)
#pragma unroll
            for (int j = 0; j < 4; ++j) {
                bf16x4 v;
#pragma unroll
                for (int g = 0; g < 4; ++g) v[g] = (bf16_t)(acc[m][g][j] + bv[g]);
                *(bf16x4*)(C + (rb + m * 16 + j) * N + cb) = v;
            }
    }
}

// ---------------------------------------------------------------------------
// GEMM3 persistent-panel: out_b = bl_b[12288,256] @ t_b[1024,256]^T, f32 NT.
// Each block owns a 96-row A-panel, stages it ONCE (96x256 bf16 = 48 KB),
// then loops all 8 nblk with B (t_b, L2-resident) double-buffered in 64-K
// chunks (2x16 KB). LDS = 80 KB -> 2 blocks/CU; 128 mblk x 8 bz = 1024
// blocks = 2 exact rounds. A HBM/L3 read traffic: 402 MB -> 50 MB (8x).
// Swizzle (both-sides, rule 21): A key (row&7) on 32 col-chunks (2-way
// conflict = free), B key ((row>>2)&7) as proven. 4 waves (2M x 2N), wave
// tile 48x64, acc[3][4]. Epilogue per nblk: 12 NT f32x4 stores, acc reset.
// ---------------------------------------------------------------------------
__global__ __launch_bounds__(256, 2)
void gemm3p(const bf16_t* __restrict__ A, const bf16_t* __restrict__ Bm,
            float* __restrict__ C, long sA, long sB, long sC) {
    extern __shared__ bf16_t lds[];
    bf16_t* Alds = lds;           // 96*256 = 24576 elems (48 KB)
    bf16_t* Blds = lds + 24576;   // 2 x [128][64] = 2 x 8192 elems (32 KB)

    const int tid  = threadIdx.x;
    const int lane = tid & 63;
    const int wave = tid >> 6;
    const int wm = wave >> 1, wn = wave & 1;
    const int lrow = lane & 15, kgrp = lane >> 4;

    const int L = blockIdx.x;
    const int bz = L & 7;          // one batch per XCD; t_b stays L2-hot
    const int mblk = L >> 3;

    const bf16_t* Ab = A + (long)bz * sA + (long)mblk * 96 * 256;
    const bf16_t* Bb = Bm + (long)bz * sB;

    // stage B 64-K chunk: step s -> nblk s>>2, kchunk s&3, buf s&1
    auto stageB = [&](int s) {
        const int nb2 = s >> 2, t2 = s & 3, buf = s & 1;
        const bf16_t* base = Bb + (long)nb2 * 128 * 256;
#pragma unroll
        for (int it = 0; it < 4; ++it) {
            const int c = it * 256 + tid, row = c >> 3;
            const int sb = (c & 7) ^ ((row >> 2) & 7);
            __builtin_amdgcn_global_load_lds(
                (const AS1 void*)(base + (long)row * 256 + t2 * 64 + sb * 8),
                (AS3 void*)(Blds + buf * 8192 + c * 8), 16, 0, 0);
        }
    };

    // prologue: full A panel (12 loads/thread) + B(0); one drain.
#pragma unroll
    for (int it = 0; it < 12; ++it) {
        const int c = it * 256 + tid;
        const int row = c >> 5, c8 = c & 31;          // 32 chunks per 256-col row
        const int s8 = c8 ^ (row & 7);                // pre-swizzled source
        __builtin_amdgcn_global_load_lds(
            (const AS1 void*)(Ab + (long)row * 256 + s8 * 8),
            (AS3 void*)(Alds + c * 8), 16, 0, 0);
    }
    stageB(0);
    asm volatile("s_waitcnt vmcnt(0)" ::: "memory");
    __builtin_amdgcn_s_barrier();

    f32x4 acc[3][4] = {};
    float* Cb = C + (long)bz * sC;
    const long rb = (long)mblk * 96 + wm * 48 + kgrp * 4;

    for (int nb = 0; nb < 8; ++nb) {
#pragma unroll
        for (int t = 0; t < 4; ++t) {
            const int s = nb * 4 + t;
            if (s < 31) stageB(s + 1);                // into buf (t+1)&1

            bf16x8 af[3][2], bfr[4][2];
#pragma unroll
            for (int m = 0; m < 3; ++m) {
                const int r = wm * 48 + m * 16 + lrow;
#pragma unroll
                for (int kk = 0; kk < 2; ++kk) {
                    const int g8 = t * 8 + kk * 4 + kgrp;       // global col-chunk
                    af[m][kk] = *(const bf16x8*)(Alds + r * 256 + (g8 ^ (r & 7)) * 8);
                }
            }
#pragma unroll
            for (int g = 0; g < 4; ++g) {
                const int r = wn * 64 + lrow * 4 + g;
#pragma unroll
                for (int kk = 0; kk < 2; ++kk)
                    bfr[g][kk] = *(const bf16x8*)(Blds + (t & 1) * 8192 + r * 64 +
                                                  ((kk * 32 + kgrp * 8) ^ (((r >> 2) & 7) << 3)));
            }

            __builtin_amdgcn_s_setprio(1);
#pragma unroll
            for (int m = 0; m < 3; ++m)
#pragma unroll
                for (int g = 0; g < 4; ++g)
#pragma unroll
                    for (int kk = 0; kk < 2; ++kk)
                        acc[m][g] = __builtin_amdgcn_mfma_f32_16x16x32_bf16(
                            af[m][kk], bfr[g][kk], acc[m][g], 0, 0, 0);
            __builtin_amdgcn_s_setprio(0);

            if (t == 3) {
                const long cb = (long)nb * 128 + wn * 64 + lrow * 4;
#pragma unroll
                for (int m = 0; m < 3; ++m)
#pragma unroll
                    for (int j = 0; j < 4; ++j) {
                        f32x4 v = { acc[m][0][j], acc[m][1][j], acc[m][2][j], acc[m][3][j] };
                        __builtin_nontemporal_store(v, (f32x4*)(Cb + (rb + m * 16 + j) * 1024 + cb));
                    }
#pragma unroll
                for (int m = 0; m < 3; ++m)
#pragma unroll
                    for (int g = 0; g < 4; ++g)
                        acc[m][g] = f32x4{0.f, 0.f, 0.f, 0.f};
            }
            __syncthreads();   // protects B dbuf reuse; drains staging + stores
        }
    }
}

// ---------------------------------------------------------------------------
// B=8, S=1024, IN=768, E=256, L=12
// ---------------------------------------------------------------------------
extern "C" void kernel_launch(void* const* d_in, const int* in_sizes, int n_in,
                              void* d_out, int out_size, void* d_ws, size_t ws_size,
                              hipStream_t stream) {
    const float* input = (const float*)d_in[0];
    const float* fc_w  = (const float*)d_in[1];
    const float* fc_b  = (const float*)d_in[2];
    const float* bi_w  = (const float*)d_in[3];
    const float* bias  = (const float*)d_in[4];

    char* ws = (char*)d_ws;
    bf16_t* inA = (bf16_t*)(ws);             // 8192*768*2
    bf16_t* wfc = (bf16_t*)(ws + 12582912);  // 256*768*2
    bf16_t* wbi = (bf16_t*)(ws + 12976128);  // 3072*256*2
    bf16_t* t   = (bf16_t*)(ws + 14548992);  // 8192*256*2
    bf16_t* bl  = (bf16_t*)(ws + 18743296);  // 8192*3072*2

    cvt_all<<<dim3(3552), dim3(256), 0, stream>>>(input, inA, fc_w, wfc, bi_w, wbi);

    // GEMM1: t = inA @ wfc^T + fc_b   (K=768; 128x64 tile -> 256 blocks, 1 round)
    gemm_bt<128, 64, 1><<<dim3(64, 4), dim3(256), 0, stream>>>(
        inA, wfc, (void*)t, fc_b, 8192, 256, 768);

    // GEMM2: bl = t @ wbi^T + bias[col&255]  (8-phase 256^2; 384 blocks)
    gemm8p<2, 0, 32, 12><<<dim3(384), dim3(512), 131072, stream>>>(
        t, wbi, (void*)bl, bias, 3072, 0L, 0L, 0L);

    // GEMM3 (batched x8): persistent 96-row panel, 1024 blocks, 2/CU, NT out
    gemm3p<<<dim3(1024), dim3(256), 81920, stream>>>(
        bl, t, (float*)d_out,
        (long)12288 * 256, (long)1024 * 256, (long)12288 * 1024);
}